// Round 1
// baseline (1755.814 us; speedup 1.0000x reference)
//
#include <hip/hip_runtime.h>
#include <math.h>

#define UNITS 50257
#define UPAD  50304   // 393 * 128
#define NEG   8192
#define CDIM  2048
#define NROWS 2048    // B*S = 2*1024
#define BM 128
#define BN 128
#define BK 32
#define LOG_RANGE_F 10.8249254f  // ln(50258)

typedef __attribute__((ext_vector_type(8))) short short8;
typedef __attribute__((ext_vector_type(4))) float floatx4;

// ---------- helpers ----------

// float -> bf16 bits, round-to-nearest-even (finite inputs only)
__device__ __forceinline__ unsigned short f2b(float f) {
  unsigned int u = __float_as_uint(f);
  unsigned int lsb = (u >> 16) & 1u;
  u += 0x7fffu + lsb;
  return (unsigned short)(u >> 16);
}

// async global->LDS, 16B per lane. LDS dest must be wave-uniform base + lane*16.
__device__ __forceinline__ void async_copy16(const void* g, void* s) {
  __builtin_amdgcn_global_load_lds(
      (const __attribute__((address_space(1))) void*)g,
      (__attribute__((address_space(3))) void*)s, 16, 0, 0);
}

// log(expected_count(log_uniform_prob(k))) -- mirrors reference fp32 formula
__device__ __forceinline__ float logq_of(int k) {
  float f = (float)k;
  float p = (logf(f + 2.0f) - logf(f + 1.0f)) / LOG_RANGE_F;
  float ec = -expm1f(8192.0f * log1pf(-p));
  return logf(ec);
}

// ---------- kernels ----------

// x fp32 [NROWS, CDIM] -> bf16 bits
__global__ void cvt_x_kernel(const float* __restrict__ x, unsigned short* __restrict__ xb) {
  int idx = blockIdx.x * 256 + threadIdx.x;  // < NROWS*CDIM/4
  float4 v = reinterpret_cast<const float4*>(x)[idx];
  unsigned long long r = (unsigned long long)f2b(v.x)
                       | ((unsigned long long)f2b(v.y) << 16)
                       | ((unsigned long long)f2b(v.z) << 32)
                       | ((unsigned long long)f2b(v.w) << 48);
  reinterpret_cast<unsigned long long*>(xb)[idx] = r;
}

// W fp32 [CDIM, UNITS] -> kT bf16 [UPAD, CDIM] (transposed, rows >= UNITS zero-filled)
__global__ void transposeW_kernel(const float* __restrict__ W, unsigned short* __restrict__ kT) {
  __shared__ float tile[32][33];
  int tx = threadIdx.x & 31, ty = threadIdx.x >> 5;  // ty 0..7
  int u0 = blockIdx.x * 32, k0 = blockIdx.y * 32;
  int u = u0 + tx;
#pragma unroll
  for (int r = 0; r < 4; r++) {
    int kk = ty + r * 8;
    tile[kk][tx] = (u < UNITS) ? W[(size_t)(k0 + kk) * UNITS + u] : 0.0f;
  }
  __syncthreads();
#pragma unroll
  for (int r = 0; r < 4; r++) {
    int uu = ty + r * 8;
    kT[(size_t)(u0 + uu) * CDIM + k0 + tx] = f2b(tile[tx][uu]);
  }
}

// kTs[j,:] = kT[sampled[j],:]  (4KB contiguous row copy, 256 threads * 16B)
__global__ void gather_rows_kernel(const unsigned short* __restrict__ kT,
                                   const int* __restrict__ sampled,
                                   unsigned short* __restrict__ kTs) {
  int j = blockIdx.x;
  int s = sampled[j];
  const uint4* src = reinterpret_cast<const uint4*>(kT + (size_t)s * CDIM);
  uint4* dst = reinterpret_cast<uint4*>(kTs + (size_t)j * CDIM);
  dst[threadIdx.x] = src[threadIdx.x];
}

__global__ void prep_logq_kernel(const int* __restrict__ sampled, float* __restrict__ lqs) {
  int j = blockIdx.x * 256 + threadIdx.x;
  if (j < NEG) lqs[j] = logq_of(sampled[j]);
}

// C[m, col] = sum_k A[m,k]*B[col,k] + bias[bidx ? bidx[col] : col]
// A: [2048, CDIM] bf16, B: [nx*128, CDIM] bf16 (K-contiguous rows), C row stride ldc.
// m97 structure: 128x128 tile, BK=32, global_load_lds width 16, 2-barrier K-loop.
__global__ __launch_bounds__(256, 2)
void gemm_bt(const unsigned short* __restrict__ A, const unsigned short* __restrict__ B,
             float* __restrict__ Cc, const float* __restrict__ bias,
             const int* __restrict__ bidx, int nx, int ldc, int colsValid)
{
  __shared__ __align__(16) unsigned short As[BM * BK];
  __shared__ __align__(16) unsigned short Bs[BN * BK];

  int tid = threadIdx.x;
  int wave = tid >> 6, lane = tid & 63;

  // panel swizzle: 16 col-tiles x 16 row-tiles co-resident => B strip read ~once
  int bid = blockIdx.x;
  const int GPC = 16;
  int panel = bid >> 8;                 // bid / (16*GPC)
  int rem = bid & 255;
  int colsInPanel = nx - panel * GPC; if (colsInPanel > GPC) colsInPanel = GPC;
  int bx = panel * GPC + (rem % colsInPanel);
  int by = rem / colsInPanel;

  int m0 = by * BM;
  int n0 = bx * BN;

  // staging: instr idx = wave*2 + r covers 16 rows (64 lanes x 16B = 16 rows x 64B)
  int sIdx = wave * 2;
  int row0 = sIdx * 16 + (lane >> 2);
  int kc = (lane & 3) * 8;
  const unsigned short* gA = A + (size_t)(m0 + row0) * CDIM + kc;
  const unsigned short* gB = B + (size_t)(n0 + row0) * CDIM + kc;
  unsigned short* lA = As + sIdx * 512 + lane * 8;
  unsigned short* lB = Bs + sIdx * 512 + lane * 8;

  floatx4 acc[4][4];
#pragma unroll
  for (int i = 0; i < 4; i++)
#pragma unroll
    for (int j = 0; j < 4; j++) acc[i][j] = (floatx4){0.f, 0.f, 0.f, 0.f};

  int wm = wave >> 1, wn = wave & 1;
  int aRow = wm * 64 + (lane & 15);
  int bRow = wn * 64 + (lane & 15);
  int kf = (lane >> 4) * 8;

  for (int kt = 0; kt < CDIM / BK; ++kt) {
    int kk = kt * BK;
    async_copy16(gA + kk, lA);
    async_copy16(gA + (size_t)16 * CDIM + kk, lA + 512);
    async_copy16(gB + kk, lB);
    async_copy16(gB + (size_t)16 * CDIM + kk, lB + 512);
    __syncthreads();

    short8 af[4], bf[4];
#pragma unroll
    for (int mi = 0; mi < 4; mi++)
      af[mi] = *(const short8*)(As + (aRow + mi * 16) * BK + kf);
#pragma unroll
    for (int ni = 0; ni < 4; ni++)
      bf[ni] = *(const short8*)(Bs + (bRow + ni * 16) * BK + kf);
#pragma unroll
    for (int mi = 0; mi < 4; mi++)
#pragma unroll
      for (int ni = 0; ni < 4; ni++)
        acc[mi][ni] = __builtin_amdgcn_mfma_f32_16x16x32_bf16(af[mi], bf[ni], acc[mi][ni], 0, 0, 0);
    __syncthreads();
  }

  // epilogue: C/D layout col=lane&15, row=(lane>>4)*4+reg (m89-verified)
  int rBase = m0 + wm * 64 + ((lane >> 4) << 2);
  int cBase = n0 + wn * 64 + (lane & 15);
#pragma unroll
  for (int mi = 0; mi < 4; mi++) {
#pragma unroll
    for (int ni = 0; ni < 4; ni++) {
      int gcol = cBase + ni * 16;
      if (gcol < colsValid) {
        float bv = bias[bidx ? bidx[gcol] : gcol];
#pragma unroll
        for (int v = 0; v < 4; v++) {
          int grow = rBase + mi * 16 + v;
          Cc[(size_t)grow * ldc + gcol] = acc[mi][ni][v] + bv;
        }
      }
    }
  }
}

// per-row online softmax (max+sum single read), capture raw true logit, normalize in place
__global__ void rownorm_kernel(float* __restrict__ logits, const int* __restrict__ targets,
                               float* __restrict__ true_logit)
{
  int i = blockIdx.x, tid = threadIdx.x;
  float* row = logits + (size_t)i * UNITS;
  int t = targets[i];
  __shared__ float red_m[4], red_s[4];

  float m = -INFINITY, s = 0.0f;
  for (int j = tid; j < UNITS; j += 256) {
    float v = row[j];
    if (j == t) true_logit[i] = v;
    float mn = fmaxf(m, v);
    s = s * __expf(m - mn) + __expf(v - mn);
    m = mn;
  }
#pragma unroll
  for (int o = 1; o < 64; o <<= 1) {
    float mo = __shfl_xor(m, o, 64);
    float so = __shfl_xor(s, o, 64);
    float mn = fmaxf(m, mo);
    s = s * __expf(m - mn) + so * __expf(mo - mn);
    m = mn;
  }
  int lane = tid & 63, wv = tid >> 6;
  if (lane == 0) { red_m[wv] = m; red_s[wv] = s; }
  __syncthreads();
  float M = fmaxf(fmaxf(red_m[0], red_m[1]), fmaxf(red_m[2], red_m[3]));
  float S = red_s[0] * __expf(red_m[0] - M) + red_s[1] * __expf(red_m[1] - M)
          + red_s[2] * __expf(red_m[2] - M) + red_s[3] * __expf(red_m[3] - M);
  float inv = 1.0f / S;
  for (int j = tid; j < UNITS; j += 256) {
    row[j] = __expf(row[j] - M) * inv;
  }
}

// per-row sampled-softmax: lse over {true_term} U {samp - logq, accidental hits removed}
__global__ void loss_rows_kernel(const float* __restrict__ samp, const int* __restrict__ sampled,
                                 const float* __restrict__ lqs, const int* __restrict__ targets,
                                 const float* __restrict__ true_logit, float* __restrict__ per_ex)
{
  int i = blockIdx.x, tid = threadIdx.x;
  int t = targets[i];
  const float* row = samp + (size_t)i * NEG;
  float tq = true_logit[i] - logq_of(t);
  __shared__ float red[4];
  int lane = tid & 63, wv = tid >> 6;

  float m = tq;
  for (int j = tid; j < NEG; j += 256) {
    if (sampled[j] == t) continue;
    m = fmaxf(m, row[j] - lqs[j]);
  }
#pragma unroll
  for (int o = 32; o > 0; o >>= 1) m = fmaxf(m, __shfl_down(m, o, 64));
  if (lane == 0) red[wv] = m;
  __syncthreads();
  m = fmaxf(fmaxf(red[0], red[1]), fmaxf(red[2], red[3]));
  __syncthreads();

  float s = (tid == 0) ? __expf(tq - m) : 0.0f;
  for (int j = tid; j < NEG; j += 256) {
    if (sampled[j] == t) continue;
    s += __expf(row[j] - lqs[j] - m);
  }
#pragma unroll
  for (int o = 32; o > 0; o >>= 1) s += __shfl_down(s, o, 64);
  if (lane == 0) red[wv] = s;
  __syncthreads();
  if (tid == 0) per_ex[i] = m + logf(red[0] + red[1] + red[2] + red[3]) - tq;
}

__global__ void loss_final_kernel(const float* __restrict__ per_ex, float* __restrict__ out) {
  __shared__ float red[4];
  int tid = threadIdx.x;
  float s = 0.0f;
  for (int j = tid; j < NROWS; j += 256) s += per_ex[j];
#pragma unroll
  for (int o = 32; o > 0; o >>= 1) s += __shfl_down(s, o, 64);
  int lane = tid & 63, wv = tid >> 6;
  if (lane == 0) red[wv] = s;
  __syncthreads();
  if (tid == 0) out[0] = (red[0] + red[1] + red[2] + red[3]) * (1.0f / (float)NROWS);
}

// ---------- launch ----------

extern "C" void kernel_launch(void* const* d_in, const int* in_sizes, int n_in,
                              void* d_out, int out_size, void* d_ws, size_t ws_size,
                              hipStream_t stream) {
  (void)in_sizes; (void)n_in; (void)out_size; (void)ws_size;
  const float* predictions = (const float*)d_in[0];
  const int*   targets     = (const int*)d_in[1];
  const float* W           = (const float*)d_in[2];
  const float* bias        = (const float*)d_in[3];
  const int*   sampled     = (const int*)d_in[4];
  float* out = (float*)d_out;

  // ws layout (~248 MB): xb | kTs | stats | kT (samp_logits aliases kT after main GEMM)
  char* ws = (char*)d_ws;
  size_t off = 0;
  unsigned short* xb  = (unsigned short*)(ws + off); off += (size_t)NROWS * CDIM * 2;  // 8.39 MB
  unsigned short* kTs = (unsigned short*)(ws + off); off += (size_t)NEG * CDIM * 2;    // 33.55 MB
  float* true_logit = (float*)(ws + off); off += (size_t)NROWS * 4;
  float* per_ex     = (float*)(ws + off); off += (size_t)NROWS * 4;
  float* lqs        = (float*)(ws + off); off += (size_t)NEG * 4;
  off = (off + 255) & ~(size_t)255;
  unsigned short* kT = (unsigned short*)(ws + off);  // UPAD*CDIM*2 = 206 MB
  float* samp = (float*)(ws + off);                  // alias: used only after kT is dead

  float* logits = out;  // [NROWS, UNITS] region of d_out

  cvt_x_kernel<<<(NROWS * CDIM / 4) / 256, 256, 0, stream>>>(predictions, xb);
  transposeW_kernel<<<dim3(UPAD / 32, CDIM / 32), 256, 0, stream>>>(W, kT);
  gather_rows_kernel<<<NEG, 256, 0, stream>>>(kT, sampled, kTs);
  prep_logq_kernel<<<NEG / 256, 256, 0, stream>>>(sampled, lqs);

  // main GEMM: logits = x @ W + bias   (reads kT)
  gemm_bt<<<(UPAD / BN) * (NROWS / BM), 256, 0, stream>>>(
      xb, kT, logits, bias, nullptr, UPAD / BN, UNITS, UNITS);
  // sampled GEMM: samp = x @ W[:,sampled] + bias[sampled]  (reads kTs, writes over kT region)
  gemm_bt<<<(NEG / BN) * (NROWS / BM), 256, 0, stream>>>(
      xb, kTs, samp, bias, sampled, NEG / BN, NEG, NEG);

  rownorm_kernel<<<NROWS, 256, 0, stream>>>(logits, targets, true_logit);
  loss_rows_kernel<<<NROWS, 256, 0, stream>>>(samp, sampled, lqs, targets, true_logit, per_ex);
  loss_final_kernel<<<1, 256, 0, stream>>>(per_ex, out + (size_t)NROWS * UNITS);
}